// Round 12
// baseline (272.451 us; speedup 1.0000x reference)
//
#include <hip/hip_runtime.h>

// TV denoiser (Chambolle-Pock), 40 iterations = 5 launches x 8 fused steps.
// Packed float4 state (x2,u0,u1,y) ping-pong; 64x128 staged -> 48x112 out.
//
// Round-24: r23 retry - DPP exchange with COMPILING boundary fix.
//   r23 post-mortem: __builtin_amdgcn_writelane undeclared on this clang
//   (readlane IS available - it compiled). Theory untested. Fix: boundary
//   lanes patched via readlane + ternary (hoisted v_cmp mask + v_cndmask,
//   all VALU pipe); __has_builtin guards prefer writelane when available
//   and degrade the whole helper to __shfl if update_dpp is missing
//   (bit-safe: only don't-care lanes differ).
//   Exclusion table (per-step ~5.5us invariant): occupancy x1.5 (r13),
//   barriers x0.5 (r14), staging reqs x1/3 (r18), shfl/cell x0.5 + grid
//   -55% (r19), VALU -25% (r22, VALUBusy 38->29% at SAME wall), DS
//   throughput (r13-vs-r19 cross-check: 2.2x DS/CU at same wall). Last
//   in-model term: per-wave SERIAL latency of 16 ds_bpermute round-trips
//   per thread-step, barrier-phase-locked so waves can't slip. This round
//   moves ALL +-1 lane exchange to the VALU pipe: v_mov_dpp row_shr:1 /
//   row_shl:1 (~2cyc, row-local per r11) + 3 readlane/select patches for
//   the row-crossing lanes (16/32/48 up, 15/31/47 down). Lane 0 (up) /
//   lane 63 (down) get 0: don't-care by the r22-VERIFIED cone/OOB proof.
//   Consumed lanes bit-identical to __shfl -> absmax EXACTLY 0.015625.
//   Cost ~+150 VALU/thread-step (headroom: VALUBusy 29%); removes 16 DS
//   round-trips/step. Predicted: win -> 45 to 32-37us/dispatch (total
//   180-205); neutral -> all in-kernel terms exonerated, declare floor.
//
// Structure (r18/r19/r22): 512 thr = 8 waves; wave s owns rows 8s..8s+7,
// lane lc owns cols 2lc,2lc+1, all in REGISTERS. Vertical: registers (+
// stride-1 LDS u0B/wTop at strip boundaries, 2-way alias = free).
// Horizontal: pair-interior in-register; cross-lane via DPP (this round).
// Image BC lives in sigH/sewf predicates (r22): SIGMA iff in-image and not
// at the far edge; OOB strips stay identically 0 by induction; staged-edge
// garbage confined by cone (1 col/step, 8 steps, stored cells 8+ away).
// first: u=0, x2=y. last: x2->out only.

#define Hh 512
#define Ww 512
#define Bb 8
#define KF 8           // fused steps per launch (5 x 8 = 40)
#define TSC 112        // output cols per block = SC - 2*KF
#define TSR 48         // output rows per block = SR - 2*KF
#define SC 128         // staged cols
#define SR 64          // staged rows
#define NT 512
#define RS 8           // rows per thread

// ---- wave-wide +-1 lane exchange on the VALU pipe ---------------------
#if __has_builtin(__builtin_amdgcn_update_dpp)

// up: lane n <- lane n-1. row_shr:1 (0x111) covers n%16!=0; patch 16/32/48
// from 15/31/47 via readlane+select; lane 0 gets 0 (don't-care, proven safe).
__device__ __forceinline__ float dpp_up1(float x, int lc) {
    int xi = __float_as_int(x);
    int d  = __builtin_amdgcn_update_dpp(0, xi, 0x111, 0xF, 0xF, true);
#if __has_builtin(__builtin_amdgcn_writelane)
    d = __builtin_amdgcn_writelane(__builtin_amdgcn_readlane(xi, 15), 16, d);
    d = __builtin_amdgcn_writelane(__builtin_amdgcn_readlane(xi, 31), 32, d);
    d = __builtin_amdgcn_writelane(__builtin_amdgcn_readlane(xi, 47), 48, d);
#else
    int f15 = __builtin_amdgcn_readlane(xi, 15);
    int f31 = __builtin_amdgcn_readlane(xi, 31);
    int f47 = __builtin_amdgcn_readlane(xi, 47);
    d = (lc == 16) ? f15 : d;        // hoisted v_cmp masks + v_cndmask
    d = (lc == 32) ? f31 : d;
    d = (lc == 48) ? f47 : d;
#endif
    return __int_as_float(d);
}
// down: lane n <- lane n+1. row_shl:1 (0x101) covers n%16!=15; patch
// 15/31/47 from 16/32/48; lane 63 gets 0 (don't-care, proven safe).
__device__ __forceinline__ float dpp_dn1(float x, int lc) {
    int xi = __float_as_int(x);
    int d  = __builtin_amdgcn_update_dpp(0, xi, 0x101, 0xF, 0xF, true);
#if __has_builtin(__builtin_amdgcn_writelane)
    d = __builtin_amdgcn_writelane(__builtin_amdgcn_readlane(xi, 16), 15, d);
    d = __builtin_amdgcn_writelane(__builtin_amdgcn_readlane(xi, 32), 31, d);
    d = __builtin_amdgcn_writelane(__builtin_amdgcn_readlane(xi, 48), 47, d);
#else
    int f16 = __builtin_amdgcn_readlane(xi, 16);
    int f32 = __builtin_amdgcn_readlane(xi, 32);
    int f48 = __builtin_amdgcn_readlane(xi, 48);
    d = (lc == 15) ? f16 : d;
    d = (lc == 31) ? f32 : d;
    d = (lc == 47) ? f48 : d;
#endif
    return __int_as_float(d);
}

#else  // no update_dpp: degrade to shfl (bit-safe; only don't-care lanes differ)
__device__ __forceinline__ float dpp_up1(float x, int lc) { return __shfl_up(x, 1, 64); }
__device__ __forceinline__ float dpp_dn1(float x, int lc) { return __shfl_down(x, 1, 64); }
#endif

// ---------------------------------------------------------------- packed --
__global__ __launch_bounds__(NT, 2)
void tv_packed(const float*  __restrict__ y_in,
               const float4* __restrict__ st_in,
               float4* __restrict__ st_out,
               float*  __restrict__ x2_out,
               int first, int last)
{
    constexpr float TAU = 0.01f;
    constexpr float RHO = 1.99f;
    constexpr float HRHO = 0.995f;       // 0.5*RHO
    constexpr float SIGMA = 12.5f;       // 1/TAU/8
    constexpr float THS = 0.1f;
    constexpr float INV_1PT = 1.0f / 1.01f;

    __shared__ float u0B [9 * SC];   // u0 of row 8s-1 (strip s-1 bottom); s=0 zeros
    __shared__ float wTop[9 * SC];   // w  of row 8s   (strip s top);     s=8 zeros

    const int b   = blockIdx.z;
    const int r0  = blockIdx.y * TSR;
    const int c0  = blockIdx.x * TSC;
    const int tid = threadIdx.x;
    const size_t plane = (size_t)b * (Hh * Ww);

    const int s     = tid >> 6;          // wave id
    const int lc    = tid & 63;          // lane id
    const int lcol0 = 2 * lc;            // first owned staged column
    const int gc0   = c0 - KF + lcol0;   // global col of c=0
    const int gc1   = gc0 + 1;
    const bool colin0 = (gc0 >= 0) & (gc0 < Ww);
    const bool colin1 = (gc1 >= 0) & (gc1 < Ww);
    // image-boundary masks, extended to kill OOB coupling (r22):
    const float sewf0 = ((gc0 >= 0) && (gc0 < Ww - 1)) ? SIGMA : 0.f;
    const float sewf1 = ((gc1 >= 0) && (gc1 < Ww - 1)) ? SIGMA : 0.f;
    const int lr0 = RS * s;
    const int gr0 = r0 - KF + lr0;

    if (tid < SC) { u0B[tid] = 0.f; wTop[8 * SC + tid] = 0.f; }

    float x2[RS][2], u0[RS][2], u1[RS][2], yv[RS][2], w[RS][2];
    float sigH[RS];                      // SIGMA iff 0 <= gr < Hh-1 (r22)

    // ---- stage: branchless, wide loads
    #pragma unroll
    for (int i = 0; i < RS; ++i) {
        const int gr = gr0 + i;
        const bool rin = (gr >= 0) & (gr < Hh);
        sigH[i] = ((gr >= 0) && (gr < Hh - 1)) ? SIGMA : 0.f;
        #pragma unroll
        for (int c = 0; c < 2; ++c) {
            const bool img = rin & (c ? colin1 : colin0);
            const size_t gi = img ? (plane + (size_t)gr * Ww + (gc0 + c)) : plane;
            if (first) {
                float cy = y_in[gi]; cy = img ? cy : 0.f;
                x2[i][c] = cy; yv[i][c] = cy; u0[i][c] = 0.f; u1[i][c] = 0.f;
            } else {
                float4 st = st_in[gi];
                x2[i][c] = img ? st.x : 0.f;
                u0[i][c] = img ? st.y : 0.f;
                u1[i][c] = img ? st.z : 0.f;
                yv[i][c] = img ? st.w : 0.f;
            }
        }
    }
    *(float2*)&u0B[(s + 1) * SC + lcol0] = make_float2(u0[RS - 1][0], u0[RS - 1][1]);
    __syncthreads();

    for (int t = 0; t < KF; ++t) {
        // ---- phase 1: w = 2x - x2 (unconditional)
        {
            float2 ua2 = *(float2*)&u0B[s * SC + lcol0];
            #pragma unroll
            for (int i = 0; i < RS; ++i) {
                float ul0 = dpp_up1(u1[i][1], lc);       // col lcol0-1 (VALU pipe)
                float ul1 = u1[i][0];                    // own register
                float ua_0 = (i == 0) ? ua2.x : u0[i - 1][0];
                float ua_1 = (i == 0) ? ua2.y : u0[i - 1][1];
                float adj0 = ua_0 - u0[i][0] + ul0 - u1[i][0];
                float adj1 = ua_1 - u0[i][1] + ul1 - u1[i][1];
                float xv0 = fmaf(TAU, yv[i][0] - adj0, x2[i][0]);
                float xv1 = fmaf(TAU, yv[i][1] - adj1, x2[i][1]);
                w[i][0] = fmaf(2.0f * INV_1PT, xv0, -x2[i][0]);
                w[i][1] = fmaf(2.0f * INV_1PT, xv1, -x2[i][1]);
            }
            *(float2*)&wTop[s * SC + lcol0] = make_float2(w[0][0], w[0][1]);
        }
        __syncthreads();
        // ---- phase 2: u, x2 update (BC in sigH/sewf; freeze proven dead)
        {
            float2 wb2 = *(float2*)&wTop[(s + 1) * SC + lcol0];
            #pragma unroll
            for (int i = 0; i < RS; ++i) {
                float wr1 = dpp_dn1(w[i][0], lc);        // col lcol0+2 (VALU pipe)
                float wr0 = w[i][1];                     // own register
                float wb_0 = (i == RS - 1) ? wb2.x : w[i + 1][0];
                float wb_1 = (i == RS - 1) ? wb2.y : w[i + 1][1];

                float v00 = fmaf(sigH[i], wb_0 - w[i][0], u0[i][0]);
                float v10 = fmaf(sewf0,   wr0 - w[i][0], u1[i][0]);
                float iv0 = fminf(THS * __builtin_amdgcn_rsqf(fmaf(v00, v00, v10 * v10)), 1.f);
                float v01 = fmaf(sigH[i], wb_1 - w[i][1], u0[i][1]);
                float v11 = fmaf(sewf1,   wr1 - w[i][1], u1[i][1]);
                float iv1 = fminf(THS * __builtin_amdgcn_rsqf(fmaf(v01, v01, v11 * v11)), 1.f);

                u0[i][0] = fmaf(RHO,  fmaf(v00, iv0, -u0[i][0]), u0[i][0]);
                u1[i][0] = fmaf(RHO,  fmaf(v10, iv0, -u1[i][0]), u1[i][0]);
                x2[i][0] = fmaf(HRHO, w[i][0] - x2[i][0], x2[i][0]);
                u0[i][1] = fmaf(RHO,  fmaf(v01, iv1, -u0[i][1]), u0[i][1]);
                u1[i][1] = fmaf(RHO,  fmaf(v11, iv1, -u1[i][1]), u1[i][1]);
                x2[i][1] = fmaf(HRHO, w[i][1] - x2[i][1], x2[i][1]);
            }
            *(float2*)&u0B[(s + 1) * SC + lcol0] = make_float2(u0[RS - 1][0], u0[RS - 1][1]);
        }
        __syncthreads();
    }

    // ---- store central 48x112 straight from registers
    #pragma unroll
    for (int c = 0; c < 2; ++c) {
        const int lcol = lcol0 + c;
        const int gc   = gc0 + c;
        if (lcol >= KF && lcol < KF + TSC && gc < Ww) {
            #pragma unroll
            for (int i = 0; i < RS; ++i) {
                const int lr = lr0 + i;
                const int gr = gr0 + i;
                if (lr >= KF && lr < KF + TSR && gr < Hh) {
                    const size_t gi = plane + (size_t)gr * Ww + gc;
                    if (last) x2_out[gi] = x2[i][c];
                    else      st_out[gi] = make_float4(x2[i][c], u0[i][c],
                                                       u1[i][c], yv[i][c]);
                }
            }
        }
    }
}

// ------------------------------------------------- fallback (exact r13) --
#define TS 48
#define S  64
#define FK 8

__global__ __launch_bounds__(NT, 3)
void tv_sep(const float*  __restrict__ x2_in,
            const float2* __restrict__ u_in,
            const float*  __restrict__ y_in,
            float*  __restrict__ x2_out,
            float2* __restrict__ u_out,
            int first, int last)
{
    constexpr float TAU = 0.01f;
    constexpr float RHO = 1.99f;
    constexpr float HRHO = 0.995f;
    constexpr float SIGMA = 12.5f;
    constexpr float THS = 0.1f;
    constexpr float INV_1PT = 1.0f / 1.01f;

    __shared__ float u0B [9 * S];
    __shared__ float wTop[9 * S];

    const int b   = blockIdx.z;
    const int r0  = blockIdx.y * TS;
    const int c0  = blockIdx.x * TS;
    const int tid = threadIdx.x;
    const size_t plane = (size_t)b * (Hh * Ww);

    const int s   = tid >> 6;
    const int lc  = tid & 63;
    const int gc  = c0 - FK + lc;
    const bool colin = (gc >= 0) & (gc < Ww);
    const float sewf = (gc < Ww - 1) ? SIGMA : 0.f;
    const int lr0 = RS * s;
    const int gr0 = r0 - FK + lr0;
    const float sigBot = (gr0 + RS - 1 == Hh - 1) ? 0.f : SIGMA;

    if (tid < S) { u0B[tid] = 0.f; wTop[8 * S + tid] = 0.f; }

    float u0[RS], u1[RS], x2[RS], yv[RS], w[RS];
    unsigned tmp0 = 0u, tmp1 = 0u;

    #pragma unroll
    for (int i = 0; i < RS; ++i) {
        const int gr = gr0 + i;
        const int lr = lr0 + i;
        const bool img = colin & (gr >= 0) & (gr < Hh);
        float a = 0.f, c = 0.f, z0 = 0.f, z1 = 0.f;
        if (img) {
            size_t gi = plane + (size_t)gr * Ww + gc;
            c = y_in[gi];
            if (first) a = c;
            else {
                a = x2_in[gi];
                float2 uu = u_in[gi];
                z0 = uu.x; z1 = uu.y;
            }
        }
        u0[i] = z0; u1[i] = z1; x2[i] = a; yv[i] = c;
        unsigned tm = img ? (unsigned)min(min(lr, S - 1 - lr), min(lc, S - 1 - lc)) : 0u;
        if (i < 4) tmp0 |= tm << (8 * i);
        else       tmp1 |= tm << (8 * (i - 4));
    }
    u0B[(s + 1) * S + lc] = u0[RS - 1];
    __syncthreads();

    for (int t = 0; t < FK; ++t) {
        {
            float u0a = u0B[s * S + lc];
            #pragma unroll
            for (int i = 0; i < RS; ++i) {
                float ul = __shfl_up(u1[i], 1, 64);
                float ua = (i == 0) ? u0a : u0[i - 1];
                float adj = ua - u0[i] + ul - u1[i];
                float xv = fmaf(TAU, yv[i] - adj, x2[i]);
                w[i] = fmaf(2.0f * INV_1PT, xv, -x2[i]);
            }
            wTop[s * S + lc] = w[0];
        }
        __syncthreads();
        {
            float wbot = wTop[(s + 1) * S + lc];
            #pragma unroll
            for (int i = 0; i < RS; ++i) {
                float wr = __shfl_down(w[i], 1, 64);
                float wb = (i == RS - 1) ? wbot : w[i + 1];
                const float sig_h = (i == RS - 1) ? sigBot : SIGMA;
                float v0 = fmaf(sig_h, wb - w[i], u0[i]);
                float v1 = fmaf(sewf,  wr - w[i], u1[i]);
                float iv = fminf(THS * __builtin_amdgcn_rsqf(fmaf(v0, v0, v1 * v1)), 1.f);
                unsigned tmb = ((i < 4 ? tmp0 : tmp1) >> (8 * (i & 3))) & 255u;
                bool act = (unsigned)t < tmb;
                float r1 = act ? RHO  : 0.f;
                float rh = act ? HRHO : 0.f;
                u0[i] = fmaf(r1, fmaf(v0, iv, -u0[i]), u0[i]);
                u1[i] = fmaf(r1, fmaf(v1, iv, -u1[i]), u1[i]);
                x2[i] = fmaf(rh, w[i] - x2[i], x2[i]);
            }
            u0B[(s + 1) * S + lc] = u0[RS - 1];
        }
        __syncthreads();
    }

    if (s >= 1 && s <= 6 && lc >= FK && lc < FK + TS && gc < Ww) {
        #pragma unroll
        for (int i = 0; i < RS; ++i) {
            const int gr = gr0 + i;
            if (gr < Hh) {
                size_t gi = plane + (size_t)gr * Ww + gc;
                x2_out[gi] = x2[i];
                if (!last) u_out[gi] = make_float2(u0[i], u1[i]);
            }
        }
    }
}

extern "C" void kernel_launch(void* const* d_in, const int* in_sizes, int n_in,
                              void* d_out, int out_size, void* d_ws, size_t ws_size,
                              hipStream_t stream)
{
    const float* y = (const float*)d_in[0];
    float* out = (float*)d_out;
    const size_t NP = (size_t)Bb * Hh * Ww;   // 2M cells

    if (ws_size >= 2 * NP * sizeof(float4)) {
        // packed path: two 32MiB float4 ping-pong buffers, 5 launches x KF=8
        float4* stA = (float4*)d_ws;
        float4* stB = stA + NP;
        dim3 grid((Ww + TSC - 1) / TSC, (Hh + TSR - 1) / TSR, Bb);  // 5x11x8 = 440
        tv_packed<<<grid, NT, 0, stream>>>(y, stB, stA, out, 1, 0);  // y -> stA
        tv_packed<<<grid, NT, 0, stream>>>(y, stA, stB, out, 0, 0);
        tv_packed<<<grid, NT, 0, stream>>>(y, stB, stA, out, 0, 0);
        tv_packed<<<grid, NT, 0, stream>>>(y, stA, stB, out, 0, 0);
        tv_packed<<<grid, NT, 0, stream>>>(y, stB, stA, out, 0, 1);  // -> out
    } else {
        // fallback: exact r13 layout (48 MiB), 5 launches x 8
        float*  ws  = (float*)d_ws;
        float*  x2A = ws;
        float*  x2B = ws + NP;
        float2* uA  = (float2*)(ws + 2 * NP);
        float2* uB  = (float2*)(ws + 4 * NP);
        dim3 grid((Ww + TS - 1) / TS, (Hh + TS - 1) / TS, Bb);      // 11x11x8
        tv_sep<<<grid, NT, 0, stream>>>(y,   uB, y, x2A, uA, 1, 0);
        tv_sep<<<grid, NT, 0, stream>>>(x2A, uA, y, x2B, uB, 0, 0);
        tv_sep<<<grid, NT, 0, stream>>>(x2B, uB, y, x2A, uA, 0, 0);
        tv_sep<<<grid, NT, 0, stream>>>(x2A, uA, y, x2B, uB, 0, 0);
        tv_sep<<<grid, NT, 0, stream>>>(x2B, uB, y, out, uA, 0, 1);
    }
}

// Round 13
// 224.244 us; speedup vs baseline: 1.2150x; 1.2150x over previous
//
#include <hip/hip_runtime.h>

// TV denoiser (Chambolle-Pock), 40 iterations = 5 launches x 8 fused steps.
// Temporal blocking: 64x64 staged region -> central 48x48 output (KF=8).
//
// Round-25: REVERT to round-18 (best measured: 222.086 us). Final state.
//   Exclusion table (per-step ~5.5us invariant): occupancy x1.5 (r13),
//   barriers x0.5 (r14), staging reqs x1/3 (r18: the only win, -2us/disp),
//   shfl/cell x0.5 + grid -55% + cells -9% (r19), launches 5->4 (r20:
//   regression), VALU -25% (r22: neutral, VALUBusy 38->29 at same wall),
//   DS->VALU-pipe exchange (r24: regression +7us). Coop/persistent-grid
//   arc (r15-r17): 2 spills + 1 container death, retired. No counter
//   saturates (VALU<=40%, HBM<=18%, conflicts 0). Wall is a structural
//   latency floor: 16 phases x (LDS visibility + barrier + wave skew),
//   clock-blind to counters (DVFS suspect). Removing work of any kind is
//   neutral; adding work hurts. This is the practical floor for this
//   decomposition on this part.
//
// Round-18: packed float4 per-cell state (x2,u0,u1,y), ping-pong buffers.
//   The staging burst was 24 scattered load insts/thread; packing the full
//   cell state into ONE float4 (y rides in .w, static passthrough) cuts it
//   to 8x global_load_dwordx4; stores one dwordx4. Branchless staging
//   (clamped addr + select). Bit-exact round-trip. ws 64MiB; ws_size GUARD
//   falls back to the r13 separate-array kernel if ws < 64MiB.
//
// Round-12/13 structure: wave = strip, cross-lane via __shfl (VERIFIED
// wave-wide on gfx950; DPP row-shifts mis-shift at 16-lane boundaries,
// and update_dpp+readlane patching costs MORE than ds_bpermute - r24).
// 512 thr = 8 waves; wave s owns rows 8s..8s+7 of all 64 staged columns
// (thread = one column x 8 rows in REGISTERS). Vertical neighbors:
// registers. Horizontal: __shfl_up(u1,1) [ph1] / __shfl_down(w,1) [ph2].
// Lane-edge clamp garbage harmless: cols lc=0/63 have tm=0 and feed only
// inactive cells (cone argument, rounds 8-10). Strip boundaries cross
// waves via stride-1 LDS u0B/wTop (4.6KB, conflict-free, single-buffered:
// read/write separated by the two per-step barriers). Masks: ph1
// unconditional; ph2 freeze via r1/rh=0 multipliers (NaN-safe: operands
// finite, rsq(0)=inf dies in fmin). tm byte-packed in 2 VGPRs. sewf/sigBot
// fold the forward-diff edge masks (unique active bottom-edge case
// by==10,s==4,i==7). first: u=0, x2=y. last: store x2 to output only.

#define Hh 512
#define Ww 512
#define Bb 8
#define TS 48
#define KF 8
#define S  64
#define NT 512
#define RS 8           // rows per strip = rows per thread

// ---------------------------------------------------------------- packed --
__global__ __launch_bounds__(NT, 3)
void tv_packed(const float*  __restrict__ y_in,
               const float4* __restrict__ st_in,
               float4* __restrict__ st_out,
               float*  __restrict__ x2_out,
               int first, int last)
{
    constexpr float TAU = 0.01f;
    constexpr float RHO = 1.99f;
    constexpr float HRHO = 0.995f;       // 0.5*RHO
    constexpr float SIGMA = 12.5f;       // 1/TAU/8
    constexpr float THS = 0.1f;
    constexpr float INV_1PT = 1.0f / 1.01f;

    __shared__ float u0B [9 * S];   // u0 of row 8s-1 (strip s-1 bottom); s=0 zeros
    __shared__ float wTop[9 * S];   // w  of row 8s   (strip s top);     s=8 zeros

    const int b   = blockIdx.z;
    const int r0  = blockIdx.y * TS;
    const int c0  = blockIdx.x * TS;
    const int tid = threadIdx.x;
    const size_t plane = (size_t)b * (Hh * Ww);

    const int s   = tid >> 6;            // wave id
    const int lc  = tid & 63;            // lane id
    const int gc  = c0 - KF + lc;
    const bool colin = (gc >= 0) & (gc < Ww);
    const float sewf = (gc < Ww - 1) ? SIGMA : 0.f;
    const int lr0 = RS * s;
    const int gr0 = r0 - KF + lr0;
    const float sigBot = (gr0 + RS - 1 == Hh - 1) ? 0.f : SIGMA;

    if (tid < S) { u0B[tid] = 0.f; wTop[8 * S + tid] = 0.f; }

    float u0[RS], u1[RS], x2[RS], yv[RS], w[RS];
    unsigned tmp0 = 0u, tmp1 = 0u;       // tm bytes

    // ---- stage: branchless, 8 wide loads
    #pragma unroll
    for (int i = 0; i < RS; ++i) {
        const int gr = gr0 + i;
        const int lr = lr0 + i;
        const bool img = colin & (gr >= 0) & (gr < Hh);
        const size_t gi = img ? (plane + (size_t)gr * Ww + gc) : plane;  // clamped, in-bounds
        if (first) {
            float c = y_in[gi];
            c = img ? c : 0.f;
            x2[i] = c; yv[i] = c; u0[i] = 0.f; u1[i] = 0.f;
        } else {
            float4 st = st_in[gi];
            x2[i] = img ? st.x : 0.f;
            u0[i] = img ? st.y : 0.f;
            u1[i] = img ? st.z : 0.f;
            yv[i] = img ? st.w : 0.f;
        }
        unsigned tm = img ? (unsigned)min(min(lr, S - 1 - lr), min(lc, S - 1 - lc)) : 0u;
        if (i < 4) tmp0 |= tm << (8 * i);
        else       tmp1 |= tm << (8 * (i - 4));
    }
    u0B[(s + 1) * S + lc] = u0[RS - 1];
    __syncthreads();

    for (int t = 0; t < KF; ++t) {
        // ---- phase 1: w = 2x - x2 (unconditional)
        {
            float u0a = u0B[s * S + lc];
            #pragma unroll
            for (int i = 0; i < RS; ++i) {
                float ul = __shfl_up(u1[i], 1, 64);
                float ua = (i == 0) ? u0a : u0[i - 1];
                float adj = ua - u0[i] + ul - u1[i];
                float xv = fmaf(TAU, yv[i] - adj, x2[i]);
                w[i] = fmaf(2.0f * INV_1PT, xv, -x2[i]);
            }
            wTop[s * S + lc] = w[0];
        }
        __syncthreads();
        // ---- phase 2: u, x2 update; freeze via r1/rh = 0
        {
            float wbot = wTop[(s + 1) * S + lc];
            #pragma unroll
            for (int i = 0; i < RS; ++i) {
                float wr = __shfl_down(w[i], 1, 64);
                float wb = (i == RS - 1) ? wbot : w[i + 1];
                const float sig_h = (i == RS - 1) ? sigBot : SIGMA;
                float v0 = fmaf(sig_h, wb - w[i], u0[i]);
                float v1 = fmaf(sewf,  wr - w[i], u1[i]);
                float iv = fminf(THS * __builtin_amdgcn_rsqf(fmaf(v0, v0, v1 * v1)), 1.f);
                unsigned tmb = ((i < 4 ? tmp0 : tmp1) >> (8 * (i & 3))) & 255u;
                bool act = (unsigned)t < tmb;
                float r1 = act ? RHO  : 0.f;
                float rh = act ? HRHO : 0.f;
                u0[i] = fmaf(r1, fmaf(v0, iv, -u0[i]), u0[i]);
                u1[i] = fmaf(r1, fmaf(v1, iv, -u1[i]), u1[i]);
                x2[i] = fmaf(rh, w[i] - x2[i], x2[i]);
            }
            u0B[(s + 1) * S + lc] = u0[RS - 1];
        }
        __syncthreads();
    }

    // ---- store central 48x48: one dwordx4 per cell (x2-only on last)
    if (s >= 1 && s <= 6 && lc >= KF && lc < KF + TS && gc < Ww) {
        #pragma unroll
        for (int i = 0; i < RS; ++i) {
            const int gr = gr0 + i;
            if (gr < Hh) {
                const size_t gi = plane + (size_t)gr * Ww + gc;
                if (last) x2_out[gi] = x2[i];
                else      st_out[gi] = make_float4(x2[i], u0[i], u1[i], yv[i]);
            }
        }
    }
}

// ------------------------------------------------- fallback (exact r13) --
__global__ __launch_bounds__(NT, 3)
void tv_sep(const float*  __restrict__ x2_in,
            const float2* __restrict__ u_in,
            const float*  __restrict__ y_in,
            float*  __restrict__ x2_out,
            float2* __restrict__ u_out,
            int first, int last)
{
    constexpr float TAU = 0.01f;
    constexpr float RHO = 1.99f;
    constexpr float HRHO = 0.995f;
    constexpr float SIGMA = 12.5f;
    constexpr float THS = 0.1f;
    constexpr float INV_1PT = 1.0f / 1.01f;

    __shared__ float u0B [9 * S];
    __shared__ float wTop[9 * S];

    const int b   = blockIdx.z;
    const int r0  = blockIdx.y * TS;
    const int c0  = blockIdx.x * TS;
    const int tid = threadIdx.x;
    const size_t plane = (size_t)b * (Hh * Ww);

    const int s   = tid >> 6;
    const int lc  = tid & 63;
    const int gc  = c0 - KF + lc;
    const bool colin = (gc >= 0) & (gc < Ww);
    const float sewf = (gc < Ww - 1) ? SIGMA : 0.f;
    const int lr0 = RS * s;
    const int gr0 = r0 - KF + lr0;
    const float sigBot = (gr0 + RS - 1 == Hh - 1) ? 0.f : SIGMA;

    if (tid < S) { u0B[tid] = 0.f; wTop[8 * S + tid] = 0.f; }

    float u0[RS], u1[RS], x2[RS], yv[RS], w[RS];
    unsigned tmp0 = 0u, tmp1 = 0u;

    #pragma unroll
    for (int i = 0; i < RS; ++i) {
        const int gr = gr0 + i;
        const int lr = lr0 + i;
        const bool img = colin & (gr >= 0) & (gr < Hh);
        float a = 0.f, c = 0.f, z0 = 0.f, z1 = 0.f;
        if (img) {
            size_t gi = plane + (size_t)gr * Ww + gc;
            c = y_in[gi];
            if (first) a = c;
            else {
                a = x2_in[gi];
                float2 uu = u_in[gi];
                z0 = uu.x; z1 = uu.y;
            }
        }
        u0[i] = z0; u1[i] = z1; x2[i] = a; yv[i] = c;
        unsigned tm = img ? (unsigned)min(min(lr, S - 1 - lr), min(lc, S - 1 - lc)) : 0u;
        if (i < 4) tmp0 |= tm << (8 * i);
        else       tmp1 |= tm << (8 * (i - 4));
    }
    u0B[(s + 1) * S + lc] = u0[RS - 1];
    __syncthreads();

    for (int t = 0; t < KF; ++t) {
        {
            float u0a = u0B[s * S + lc];
            #pragma unroll
            for (int i = 0; i < RS; ++i) {
                float ul = __shfl_up(u1[i], 1, 64);
                float ua = (i == 0) ? u0a : u0[i - 1];
                float adj = ua - u0[i] + ul - u1[i];
                float xv = fmaf(TAU, yv[i] - adj, x2[i]);
                w[i] = fmaf(2.0f * INV_1PT, xv, -x2[i]);
            }
            wTop[s * S + lc] = w[0];
        }
        __syncthreads();
        {
            float wbot = wTop[(s + 1) * S + lc];
            #pragma unroll
            for (int i = 0; i < RS; ++i) {
                float wr = __shfl_down(w[i], 1, 64);
                float wb = (i == RS - 1) ? wbot : w[i + 1];
                const float sig_h = (i == RS - 1) ? sigBot : SIGMA;
                float v0 = fmaf(sig_h, wb - w[i], u0[i]);
                float v1 = fmaf(sewf,  wr - w[i], u1[i]);
                float iv = fminf(THS * __builtin_amdgcn_rsqf(fmaf(v0, v0, v1 * v1)), 1.f);
                unsigned tmb = ((i < 4 ? tmp0 : tmp1) >> (8 * (i & 3))) & 255u;
                bool act = (unsigned)t < tmb;
                float r1 = act ? RHO  : 0.f;
                float rh = act ? HRHO : 0.f;
                u0[i] = fmaf(r1, fmaf(v0, iv, -u0[i]), u0[i]);
                u1[i] = fmaf(r1, fmaf(v1, iv, -u1[i]), u1[i]);
                x2[i] = fmaf(rh, w[i] - x2[i], x2[i]);
            }
            u0B[(s + 1) * S + lc] = u0[RS - 1];
        }
        __syncthreads();
    }

    if (s >= 1 && s <= 6 && lc >= KF && lc < KF + TS && gc < Ww) {
        #pragma unroll
        for (int i = 0; i < RS; ++i) {
            const int gr = gr0 + i;
            if (gr < Hh) {
                size_t gi = plane + (size_t)gr * Ww + gc;
                x2_out[gi] = x2[i];
                if (!last) u_out[gi] = make_float2(u0[i], u1[i]);
            }
        }
    }
}

extern "C" void kernel_launch(void* const* d_in, const int* in_sizes, int n_in,
                              void* d_out, int out_size, void* d_ws, size_t ws_size,
                              hipStream_t stream)
{
    const float* y = (const float*)d_in[0];
    float* out = (float*)d_out;
    const size_t NP = (size_t)Bb * Hh * Ww;   // 2M cells

    dim3 grid((Ww + TS - 1) / TS, (Hh + TS - 1) / TS, Bb);   // 11 x 11 x 8 = 968

    if (ws_size >= 2 * NP * sizeof(float4)) {
        // packed path: two 32MiB float4 ping-pong buffers
        float4* stA = (float4*)d_ws;
        float4* stB = stA + NP;
        tv_packed<<<grid, NT, 0, stream>>>(y, stB, stA, out, 1, 0);  // y -> stA
        tv_packed<<<grid, NT, 0, stream>>>(y, stA, stB, out, 0, 0);
        tv_packed<<<grid, NT, 0, stream>>>(y, stB, stA, out, 0, 0);
        tv_packed<<<grid, NT, 0, stream>>>(y, stA, stB, out, 0, 0);
        tv_packed<<<grid, NT, 0, stream>>>(y, stB, stA, out, 0, 1);  // -> out
    } else {
        // fallback: exact r13 layout (48 MiB)
        float*  ws  = (float*)d_ws;
        float*  x2A = ws;
        float*  x2B = ws + NP;
        float2* uA  = (float2*)(ws + 2 * NP);
        float2* uB  = (float2*)(ws + 4 * NP);
        tv_sep<<<grid, NT, 0, stream>>>(y,   uB, y, x2A, uA, 1, 0);
        tv_sep<<<grid, NT, 0, stream>>>(x2A, uA, y, x2B, uB, 0, 0);
        tv_sep<<<grid, NT, 0, stream>>>(x2B, uB, y, x2A, uA, 0, 0);
        tv_sep<<<grid, NT, 0, stream>>>(x2A, uA, y, x2B, uB, 0, 0);
        tv_sep<<<grid, NT, 0, stream>>>(x2B, uB, y, out, uA, 0, 1);
    }
}